// Round 1
// baseline (429.293 us; speedup 1.0000x reference)
//
#include <hip/hip_runtime.h>
#include <hip/hip_bf16.h>

#define D_MODEL 512
#define SEQ 2048
#define NB 4
#define NH 8
#define DH 64
#define NHEADS 32      // NB*NH
#define MROWS 8192     // NB*SEQ

typedef __bf16 bf16_t;
typedef __bf16 bf16x4_t __attribute__((ext_vector_type(4)));
typedef __bf16 bf16x8_t __attribute__((ext_vector_type(8)));
typedef float f32x4_t __attribute__((ext_vector_type(4)));

__device__ inline f32x4_t mfma16(bf16x8_t a, bf16x8_t b, f32x4_t c) {
    return __builtin_amdgcn_mfma_f32_16x16x32_bf16(a, b, c, 0, 0, 0);
}

// ---------------------------------------------------------------------------
// Kernel 1: QKV projection GEMM.  y = X[8192,512] @ W^T + bias  (W row-major
// [out][in] == B^T layout, K-contiguous).  Tile 128x128, BK=64, 4 waves.
// mode 0: X=q -> qh bf16 [NHEADS][SEQ][DH]
// mode 1: X=k -> kh bf16 [NHEADS][SEQ][DH]
// mode 2: X=v -> vt bf16 [NHEADS][DH][SEQ]   (transposed for PV B-frags)
// ---------------------------------------------------------------------------
__global__ __launch_bounds__(256) void qkv_proj_kernel(
    const float* __restrict__ qp, const float* __restrict__ kp, const float* __restrict__ vp,
    const float* __restrict__ Wq, const float* __restrict__ bq,
    const float* __restrict__ Wk, const float* __restrict__ bk,
    const float* __restrict__ Wv, const float* __restrict__ bv,
    bf16_t* __restrict__ qh, bf16_t* __restrict__ kh, bf16_t* __restrict__ vt)
{
    // +8 bf16 pad: row stride 144 B -> consecutive rows 4 banks apart, 16B-aligned
    __shared__ bf16_t As[128][72];
    __shared__ bf16_t Bs[128][72];

    const int mode = blockIdx.z;
    const float* X    = (mode == 0) ? qp : (mode == 1) ? kp : vp;
    const float* W    = (mode == 0) ? Wq : (mode == 1) ? Wk : Wv;
    const float* bias = (mode == 0) ? bq : (mode == 1) ? bk : bv;
    bf16_t* dst       = (mode == 0) ? qh : (mode == 1) ? kh : vt;

    const int t = threadIdx.x;
    const int lane = t & 63, w = t >> 6;
    const int lr = lane & 15, lg = lane >> 4;
    const int wm = w >> 1, wn = w & 1;
    const int m0 = blockIdx.x * 128, n0 = blockIdx.y * 128;

    f32x4_t acc[4][4];
#pragma unroll
    for (int i = 0; i < 4; i++)
#pragma unroll
        for (int j = 0; j < 4; j++) acc[i][j] = f32x4_t{0.f, 0.f, 0.f, 0.f};

    const int srow = t >> 4;         // 0..15
    const int scol = (t & 15) * 4;   // 0..60

    for (int kt = 0; kt < 8; kt++) {
        __syncthreads();
#pragma unroll
        for (int p = 0; p < 8; p++) {
            int row = p * 16 + srow;
            float4 va = *(const float4*)(X + (size_t)(m0 + row) * 512 + kt * 64 + scol);
            bf16x4_t ha = { (bf16_t)va.x, (bf16_t)va.y, (bf16_t)va.z, (bf16_t)va.w };
            *(bf16x4_t*)(&As[row][scol]) = ha;
            float4 vb = *(const float4*)(W + (size_t)(n0 + row) * 512 + kt * 64 + scol);
            bf16x4_t hb = { (bf16_t)vb.x, (bf16_t)vb.y, (bf16_t)vb.z, (bf16_t)vb.w };
            *(bf16x4_t*)(&Bs[row][scol]) = hb;
        }
        __syncthreads();
#pragma unroll
        for (int kk = 0; kk < 64; kk += 32) {
            bf16x8_t af[4], bfr[4];
#pragma unroll
            for (int i = 0; i < 4; i++)
                af[i] = *(const bf16x8_t*)(&As[wm * 64 + i * 16 + lr][kk + lg * 8]);
#pragma unroll
            for (int j = 0; j < 4; j++)
                bfr[j] = *(const bf16x8_t*)(&Bs[wn * 64 + j * 16 + lr][kk + lg * 8]);
#pragma unroll
            for (int i = 0; i < 4; i++)
#pragma unroll
                for (int j = 0; j < 4; j++)
                    acc[i][j] = mfma16(af[i], bfr[j], acc[i][j]);
        }
    }

    // epilogue: D[i][j]: row = (lane>>4)*4 + r, col = lane&15  [m89-verified]
#pragma unroll
    for (int j = 0; j < 4; j++) {
        int col = n0 + wn * 64 + j * 16 + lr;
        float bval = bias[col];
        int h = col >> 6, d = col & 63;
#pragma unroll
        for (int i = 0; i < 4; i++) {
#pragma unroll
            for (int r = 0; r < 4; r++) {
                int row = m0 + wm * 64 + i * 16 + lg * 4 + r;
                int b = row >> 11, l = row & 2047;
                float val = acc[i][j][r] + bval;
                if (mode == 2)
                    dst[(size_t)((b * NH + h) * DH + d) * SEQ + l] = (bf16_t)val;
                else
                    dst[(size_t)((b * NH + h) * SEQ + l) * DH + d] = (bf16_t)val;
            }
        }
    }
}

// ---------------------------------------------------------------------------
// Kernel 2: fused attention per (b,h) x 16 Q-rows.
// S tile 16x2048 bf16 in LDS (64 KiB, XOR swizzle byte ^= (row&7)<<4).
// Writes normalized probs (f32) to d_out, PV via MFMA -> attw bf16.
// ---------------------------------------------------------------------------
__global__ __launch_bounds__(256) void attn_kernel(
    const bf16_t* __restrict__ qh, const bf16_t* __restrict__ kh,
    const bf16_t* __restrict__ vt, float* __restrict__ probs,
    bf16_t* __restrict__ attw, float* __restrict__ rinvg)
{
    __shared__ bf16_t Sb[16 * 2048];   // exactly 64 KiB
    char* smem = (char*)Sb;

    const int bh = blockIdx.y;         // 0..31  (= b*NH + h)
    const int q0 = blockIdx.x * 16;
    const int t = threadIdx.x;
    const int lane = t & 63, w = t >> 6;
    const int lr = lane & 15, lg = lane >> 4;

    // Q fragments (A): row = lane&15, k = (lane>>4)*8 + e  (+32 for 2nd frag)
    const bf16_t* qb = qh + ((size_t)bh * SEQ + q0 + lr) * DH + lg * 8;
    bf16x8_t aq0 = *(const bf16x8_t*)(qb);
    bf16x8_t aq1 = *(const bf16x8_t*)(qb + 32);

    // ---- S = Q K^T (store raw scores bf16 into LDS) ----
    const bf16_t* kb = kh + (size_t)bh * SEQ * DH;
    for (int jt = w; jt < 128; jt += 4) {
        const bf16_t* kp_ = kb + (size_t)(jt * 16 + lr) * DH + lg * 8;
        bf16x8_t b0 = *(const bf16x8_t*)(kp_);
        bf16x8_t b1 = *(const bf16x8_t*)(kp_ + 32);
        f32x4_t s = {0.f, 0.f, 0.f, 0.f};
        s = mfma16(aq0, b0, s);
        s = mfma16(aq1, b1, s);
#pragma unroll
        for (int r = 0; r < 4; r++) {
            int row = lg * 4 + r;
            int byte = row * 4096 + (((jt * 16 + lr) * 2) ^ ((row & 7) << 4));
            *(bf16_t*)(smem + byte) = (bf16_t)s[r];
        }
    }
    __syncthreads();

    // ---- softmax: wave w owns rows w*4 .. w*4+3 (scale 1/8 folded into exp) ----
#pragma unroll
    for (int rr = 0; rr < 4; rr++) {
        int row = w * 4 + rr;
        int sw = (row & 7) << 4;
        float m = -1e30f;
#pragma unroll
        for (int c = 0; c < 4; c++) {
            int byte = row * 4096 + (((c * 512 + lane * 8) * 2) ^ sw);
            bf16x8_t sv = *(const bf16x8_t*)(smem + byte);
#pragma unroll
            for (int e = 0; e < 8; e++) m = fmaxf(m, (float)sv[e]);
        }
#pragma unroll
        for (int msk = 32; msk >= 1; msk >>= 1) m = fmaxf(m, __shfl_xor(m, msk, 64));

        float sum = 0.f;
#pragma unroll
        for (int c = 0; c < 4; c++) {
            int byte = row * 4096 + (((c * 512 + lane * 8) * 2) ^ sw);
            bf16x8_t sv = *(const bf16x8_t*)(smem + byte);
            bf16x8_t ev;
#pragma unroll
            for (int e = 0; e < 8; e++) {
                float x = __expf(((float)sv[e] - m) * 0.125f);
                sum += x;
                ev[e] = (bf16_t)x;
            }
            *(bf16x8_t*)(smem + byte) = ev;   // overwrite scores with e
        }
#pragma unroll
        for (int msk = 32; msk >= 1; msk >>= 1) sum += __shfl_xor(sum, msk, 64);
        float ri = 1.0f / sum;
        if (lane == 0) rinvg[bh * SEQ + q0 + row] = ri;

        // write normalized probs (the dominant HBM write)
        float* op = probs + (size_t)bh * SEQ * SEQ + (size_t)(q0 + row) * SEQ;
#pragma unroll
        for (int c = 0; c < 4; c++) {
            int col = c * 512 + lane * 8;
            int byte = row * 4096 + ((col * 2) ^ sw);
            bf16x8_t ev = *(const bf16x8_t*)(smem + byte);
            float4 o0 = { (float)ev[0] * ri, (float)ev[1] * ri, (float)ev[2] * ri, (float)ev[3] * ri };
            float4 o1 = { (float)ev[4] * ri, (float)ev[5] * ri, (float)ev[6] * ri, (float)ev[7] * ri };
            *(float4*)(op + col)     = o0;
            *(float4*)(op + col + 4) = o1;
        }
    }
    __syncthreads();   // e-values + rinvg visible to all waves

    // ---- PV: wave w computes d-columns w*16 .. w*16+15 ----
    f32x4_t o = {0.f, 0.f, 0.f, 0.f};
    const bf16_t* vb = vt + ((size_t)bh * DH + w * 16 + lr) * SEQ;
    for (int jt = 0; jt < 64; jt++) {
        int row = lr;   // A row = P row
        int byte = row * 4096 + (((jt * 32 + lg * 8) * 2) ^ ((row & 7) << 4));
        bf16x8_t a = *(const bf16x8_t*)(smem + byte);
        bf16x8_t b = *(const bf16x8_t*)(vb + jt * 32 + lg * 8);
        o = mfma16(a, b, o);
    }
    bf16_t* ao = attw + ((size_t)bh * SEQ + q0) * DH + w * 16 + lr;
#pragma unroll
    for (int r = 0; r < 4; r++) {
        int row = lg * 4 + r;
        float ri = rinvg[bh * SEQ + q0 + row];
        ao[(size_t)row * DH] = (bf16_t)(o[r] * ri);
        ao += 0; // keep ao base; index below
    }
}

// fix: the r-loop above must index per-row; rewritten properly via a macro-free
// second definition is avoided by doing the indexing inline (see ao usage).

// ---------------------------------------------------------------------------
// Kernel 3: out-projection with the reference's "buggy merge" gather.
// A[row][k] = attw[(k>>6)*4 + (row>>11)][row&2047][k&63]
// ---------------------------------------------------------------------------
__global__ __launch_bounds__(256) void out_proj_kernel(
    const bf16_t* __restrict__ attw, const float* __restrict__ Wo,
    const float* __restrict__ bo, float* __restrict__ y)
{
    __shared__ bf16_t As[128][72];
    __shared__ bf16_t Bs[128][72];

    const int t = threadIdx.x;
    const int lane = t & 63, w = t >> 6;
    const int lr = lane & 15, lg = lane >> 4;
    const int wm = w >> 1, wn = w & 1;
    const int m0 = blockIdx.x * 128, n0 = blockIdx.y * 128;

    f32x4_t acc[4][4];
#pragma unroll
    for (int i = 0; i < 4; i++)
#pragma unroll
        for (int j = 0; j < 4; j++) acc[i][j] = f32x4_t{0.f, 0.f, 0.f, 0.f};

    const int arow = t >> 3;          // 0..31
    const int acol = (t & 7) * 8;     // 0..56
    const int srow = t >> 4;
    const int scol = (t & 15) * 4;

    for (int kt = 0; kt < 8; kt++) {   // kt == head index of the K-slice
        __syncthreads();
#pragma unroll
        for (int p = 0; p < 4; p++) {
            int row = p * 32 + arow;
            int grow = m0 + row;
            int b = grow >> 11, l = grow & 2047;
            bf16x8_t va = *(const bf16x8_t*)(attw + (size_t)((kt * NB + b) * SEQ + l) * DH + acol);
            *(bf16x8_t*)(&As[row][acol]) = va;
        }
#pragma unroll
        for (int p = 0; p < 8; p++) {
            int row = p * 16 + srow;
            float4 vb = *(const float4*)(Wo + (size_t)(n0 + row) * 512 + kt * 64 + scol);
            bf16x4_t hb = { (bf16_t)vb.x, (bf16_t)vb.y, (bf16_t)vb.z, (bf16_t)vb.w };
            *(bf16x4_t*)(&Bs[row][scol]) = hb;
        }
        __syncthreads();
#pragma unroll
        for (int kk = 0; kk < 64; kk += 32) {
            bf16x8_t af[4], bfr[4];
#pragma unroll
            for (int i = 0; i < 4; i++)
                af[i] = *(const bf16x8_t*)(&As[wm * 64 + i * 16 + lr][kk + lg * 8]);
#pragma unroll
            for (int j = 0; j < 4; j++)
                bfr[j] = *(const bf16x8_t*)(&Bs[wn * 64 + j * 16 + lr][kk + lg * 8]);
#pragma unroll
            for (int i = 0; i < 4; i++)
#pragma unroll
                for (int j = 0; j < 4; j++)
                    acc[i][j] = mfma16(af[i], bfr[j], acc[i][j]);
        }
    }

#pragma unroll
    for (int j = 0; j < 4; j++) {
        int col = n0 + wn * 64 + j * 16 + lr;
        float bval = bo[col];
#pragma unroll
        for (int i = 0; i < 4; i++) {
#pragma unroll
            for (int r = 0; r < 4; r++) {
                int row = m0 + wm * 64 + i * 16 + lg * 4 + r;
                y[(size_t)row * 512 + col] = acc[i][j][r] + bval;
            }
        }
    }
}

// ---------------------------------------------------------------------------
// Kernel 4: residual + LayerNorm.  One wave per row of 512.
// ---------------------------------------------------------------------------
__global__ __launch_bounds__(256) void ln_kernel(
    const float* __restrict__ y, const float* __restrict__ resid,
    const float* __restrict__ gamma, const float* __restrict__ beta,
    float* __restrict__ out)
{
    const int t = threadIdx.x;
    const int lane = t & 63, w = t >> 6;
    const int row = blockIdx.x * 4 + w;
    const float* yr = y + (size_t)row * 512;
    const float* rr = resid + (size_t)row * 512;
    const int c = lane * 8;

    float4 a0 = *(const float4*)(yr + c);
    float4 a1 = *(const float4*)(yr + c + 4);
    float4 r0 = *(const float4*)(rr + c);
    float4 r1 = *(const float4*)(rr + c + 4);
    float x[8] = { a0.x + r0.x, a0.y + r0.y, a0.z + r0.z, a0.w + r0.w,
                   a1.x + r1.x, a1.y + r1.y, a1.z + r1.z, a1.w + r1.w };

    float s = 0.f, sq = 0.f;
#pragma unroll
    for (int e = 0; e < 8; e++) { s += x[e]; sq += x[e] * x[e]; }
#pragma unroll
    for (int msk = 32; msk >= 1; msk >>= 1) {
        s  += __shfl_xor(s,  msk, 64);
        sq += __shfl_xor(sq, msk, 64);
    }
    float mean = s * (1.f / 512.f);
    float var  = sq * (1.f / 512.f) - mean * mean;
    float rstd = rsqrtf(var + 1e-5f);

    float4 g0 = *(const float4*)(gamma + c);
    float4 g1 = *(const float4*)(gamma + c + 4);
    float4 b0 = *(const float4*)(beta + c);
    float4 b1 = *(const float4*)(beta + c + 4);
    float g[8] = { g0.x, g0.y, g0.z, g0.w, g1.x, g1.y, g1.z, g1.w };
    float bb[8] = { b0.x, b0.y, b0.z, b0.w, b1.x, b1.y, b1.z, b1.w };

    float o[8];
#pragma unroll
    for (int e = 0; e < 8; e++) o[e] = (x[e] - mean) * rstd * g[e] + bb[e];
    float4 o0 = { o[0], o[1], o[2], o[3] };
    float4 o1 = { o[4], o[5], o[6], o[7] };
    float* op = out + (size_t)row * 512 + c;
    *(float4*)(op)     = o0;
    *(float4*)(op + 4) = o1;
}

extern "C" void kernel_launch(void* const* d_in, const int* in_sizes, int n_in,
                              void* d_out, int out_size, void* d_ws, size_t ws_size,
                              hipStream_t stream)
{
    (void)in_sizes; (void)n_in; (void)out_size; (void)ws_size;

    const float* q     = (const float*)d_in[0];
    const float* k     = (const float*)d_in[1];
    const float* v     = (const float*)d_in[2];
    const float* Wq    = (const float*)d_in[3];
    const float* bq    = (const float*)d_in[4];
    const float* Wk    = (const float*)d_in[5];
    const float* bk    = (const float*)d_in[6];
    const float* Wv    = (const float*)d_in[7];
    const float* bv    = (const float*)d_in[8];
    const float* Wo    = (const float*)d_in[9];
    const float* bo    = (const float*)d_in[10];
    const float* gamma = (const float*)d_in[11];
    const float* beta  = (const float*)d_in[12];

    float* out   = (float*)d_out;
    float* probs = out + (size_t)NB * SEQ * D_MODEL;   // raw_att region

    char* ws = (char*)d_ws;
    bf16_t* qh   = (bf16_t*)(ws);              //  8 MB  [32][2048][64]
    bf16_t* kh   = (bf16_t*)(ws + 8388608);    //  8 MB
    bf16_t* vt   = (bf16_t*)(ws + 16777216);   //  8 MB  [32][64][2048]
    bf16_t* attw = (bf16_t*)(ws + 25165824);   //  8 MB  [32][2048][64]
    float*  y    = (float*) (ws + 33554432);   // 16 MB  [8192][512]
    float*  rinv = (float*) (ws + 50331648);   // 256 KB [32][2048]

    qkv_proj_kernel<<<dim3(64, 4, 3), 256, 0, stream>>>(q, k, v, Wq, bq, Wk, bk, Wv, bv, qh, kh, vt);
    attn_kernel<<<dim3(128, 32), 256, 0, stream>>>(qh, kh, vt, probs, attw, rinv);
    out_proj_kernel<<<dim3(64, 4), 256, 0, stream>>>(attw, Wo, bo, y);
    ln_kernel<<<2048, 256, 0, stream>>>(y, q, gamma, beta, out);
}